// Round 1
// baseline (286.046 us; speedup 1.0000x reference)
//
#include <hip/hip_runtime.h>
#include <hip/hip_bf16.h>
#include <stdint.h>

typedef unsigned short u16;
typedef __attribute__((ext_vector_type(8))) __bf16 bf16x8;
typedef __attribute__((ext_vector_type(4))) float f32x4;

#define DEV static __device__ __forceinline__

DEV u16 f32_to_bf16(float f) {
  uint32_t u = __float_as_uint(f);
  u += 0x7fffu + ((u >> 16) & 1u);   // round-to-nearest-even
  return (u16)(u >> 16);
}

DEV void unpack8(uint4 u, float* f) {
  uint32_t a[4] = {u.x, u.y, u.z, u.w};
#pragma unroll
  for (int i = 0; i < 4; ++i) {
    f[2 * i]     = __uint_as_float(a[i] << 16);
    f[2 * i + 1] = __uint_as_float(a[i] & 0xffff0000u);
  }
}

DEV uint4 pack8(const float* f) {
  uint32_t a[4];
#pragma unroll
  for (int i = 0; i < 4; ++i)
    a[i] = (uint32_t)f32_to_bf16(f[2 * i]) | ((uint32_t)f32_to_bf16(f[2 * i + 1]) << 16);
  return make_uint4(a[0], a[1], a[2], a[3]);
}

// ---------------------------------------------------------------------------
// Kernel 1: f32 -> bf16 conversion of x (65536x256) and the 4 weight matrices.
// wqkv = concat(Wq, Wk, Wv) rows (768x256), wob = Wo (256x256).
// ---------------------------------------------------------------------------
__global__ __launch_bounds__(256) void convert_kernel(
    const float* __restrict__ x, const float* __restrict__ Wq,
    const float* __restrict__ Wk, const float* __restrict__ Wv,
    const float* __restrict__ Wo, u16* __restrict__ xb,
    u16* __restrict__ wqkv, u16* __restrict__ wob) {
  const size_t NX4 = (size_t)65536 * 256 / 4;  // 4,194,304 float4 chunks of x
  size_t i = (size_t)blockIdx.x * 256 + threadIdx.x;
  const float* src;
  u16* dst;
  size_t off4;
  if (i < NX4) {
    src = x; dst = xb; off4 = i;
  } else {
    size_t w = i - NX4;            // [0, 65536)
    int which = (int)(w >> 14);    // 16384 float4 per 256x256 matrix
    off4 = w & 16383;
    if (which == 0)      { src = Wq; dst = wqkv; }
    else if (which == 1) { src = Wk; dst = wqkv + 65536; }
    else if (which == 2) { src = Wv; dst = wqkv + 131072; }
    else                 { src = Wo; dst = wob; }
  }
  float4 v = reinterpret_cast<const float4*>(src)[off4];
  ushort4 o;
  o.x = f32_to_bf16(v.x); o.y = f32_to_bf16(v.y);
  o.z = f32_to_bf16(v.z); o.w = f32_to_bf16(v.w);
  reinterpret_cast<ushort4*>(dst)[off4] = o;
}

// ---------------------------------------------------------------------------
// Kernel 2: QKV projection.  C(65536x768) = Xb(65536x256) @ Wqkv^T + bias,
// output bf16.  128x128 tile, BK=32, 4 waves (2x2), 16x16x32 bf16 MFMA.
// LDS rows padded to 40 elems (80B) so frag ds_read_b128 is conflict-free-ish.
// ---------------------------------------------------------------------------
__global__ __launch_bounds__(256) void qkv_gemm(
    const u16* __restrict__ Xb, const u16* __restrict__ Wqkv,
    const float* __restrict__ bq, const float* __restrict__ bk,
    const float* __restrict__ bv, u16* __restrict__ QKV) {
  __shared__ u16 As[128][40];
  __shared__ u16 Bs[128][40];
  const int bn = blockIdx.x;  // 0..5  (cols of 128)
  const int bm = blockIdx.y;  // 0..511 (rows of 128)
  const int tid = threadIdx.x;
  const int lane = tid & 63;
  const int wid = tid >> 6;
  const int wm = (wid >> 1) * 64;
  const int wn = (wid & 1) * 64;
  const int fr = lane & 15;
  const int fq = lane >> 4;

  f32x4 acc[4][4] = {};

  const int tr = tid >> 1;           // staging row 0..127
  const int tc = (tid & 1) << 4;     // staging col base 0 / 16
  const u16* Ag = Xb + (size_t)(bm * 128 + tr) * 256 + tc;
  const u16* Bg = Wqkv + (size_t)(bn * 128 + tr) * 256 + tc;

  for (int kt = 0; kt < 8; ++kt) {
    uint4 a0 = *reinterpret_cast<const uint4*>(Ag + kt * 32);
    uint4 a1 = *reinterpret_cast<const uint4*>(Ag + kt * 32 + 8);
    uint4 b0 = *reinterpret_cast<const uint4*>(Bg + kt * 32);
    uint4 b1 = *reinterpret_cast<const uint4*>(Bg + kt * 32 + 8);
    __syncthreads();
    *reinterpret_cast<uint4*>(&As[tr][tc]) = a0;
    *reinterpret_cast<uint4*>(&As[tr][tc + 8]) = a1;
    *reinterpret_cast<uint4*>(&Bs[tr][tc]) = b0;
    *reinterpret_cast<uint4*>(&Bs[tr][tc + 8]) = b1;
    __syncthreads();
    bf16x8 af[4], bf[4];
#pragma unroll
    for (int m = 0; m < 4; ++m)
      af[m] = *reinterpret_cast<const bf16x8*>(&As[wm + m * 16 + fr][fq * 8]);
#pragma unroll
    for (int n = 0; n < 4; ++n)
      bf[n] = *reinterpret_cast<const bf16x8*>(&Bs[wn + n * 16 + fr][fq * 8]);
#pragma unroll
    for (int m = 0; m < 4; ++m)
#pragma unroll
      for (int n = 0; n < 4; ++n)
        acc[m][n] = __builtin_amdgcn_mfma_f32_16x16x32_bf16(af[m], bf[n], acc[m][n], 0, 0, 0);
  }

  // bias: block cols [bn*128, +128): bn 0-1 -> bq, 2-3 -> bk, 4-5 -> bv
  const float* bias = (bn < 2) ? (bq + (bn & 1) * 128)
                    : (bn < 4) ? (bk + ((bn - 2) & 1) * 128)
                               : (bv + ((bn - 4) & 1) * 128);
  float bv4[4];
#pragma unroll
  for (int n = 0; n < 4; ++n) bv4[n] = bias[wn + n * 16 + fr];

#pragma unroll
  for (int m = 0; m < 4; ++m) {
#pragma unroll
    for (int r = 0; r < 4; ++r) {
      int row = bm * 128 + wm + m * 16 + fq * 4 + r;
      u16* orow = QKV + (size_t)row * 768 + bn * 128;
#pragma unroll
      for (int n = 0; n < 4; ++n)
        orow[wn + n * 16 + fr] = f32_to_bf16(acc[m][n][r] + bv4[n]);
    }
  }
}

// ---------------------------------------------------------------------------
// Kernel 3: windowed attention.  qkv layout: row=(b*S+s), col: [0,256)=Q,
// [256,512)=K, [512,768)=V, head h at h*64.  One wave = 8 windows
// (8 lanes/window, 8 dims/lane).  Padded rows (s>=S) are exact zeros, kept
// in the softmax, matching the reference's zero-padding semantics.
// ---------------------------------------------------------------------------
__global__ __launch_bounds__(256) void attn_kernel(const u16* __restrict__ QKV,
                                                   u16* __restrict__ AO) {
  const int S = 8192, NW = 1639, CH = 205;  // CH = ceil(1639/8)
  int wgid = blockIdx.x * 4 + (threadIdx.x >> 6);
  int lane = threadIdx.x & 63;
  int b = wgid / (4 * CH);
  int rm = wgid % (4 * CH);
  int h = rm / CH;
  int ch = rm % CH;
  int w = ch * 8 + (lane >> 3);
  int t = lane & 7;
  bool wv = (w < NW);

  float kv[5][8], vv[5][8];
#pragma unroll
  for (int j = 0; j < 5; ++j) {
    int s = w * 5 + j;
    if (wv && s < S) {
      size_t off = ((size_t)b * S + s) * 768 + h * 64 + t * 8;
      unpack8(*reinterpret_cast<const uint4*>(QKV + off + 256), kv[j]);
      unpack8(*reinterpret_cast<const uint4*>(QKV + off + 512), vv[j]);
    } else {
#pragma unroll
      for (int d = 0; d < 8; ++d) { kv[j][d] = 0.f; vv[j][d] = 0.f; }
    }
  }

#pragma unroll
  for (int i = 0; i < 5; ++i) {
    int s = w * 5 + i;
    bool sv = wv && (s < S);
    float q[8];
    if (sv) {
      size_t off = ((size_t)b * S + s) * 768 + h * 64 + t * 8;
      unpack8(*reinterpret_cast<const uint4*>(QKV + off), q);
    } else {
#pragma unroll
      for (int d = 0; d < 8; ++d) q[d] = 0.f;
    }
    float sc[5];
#pragma unroll
    for (int j = 0; j < 5; ++j) {
      float p = 0.f;
#pragma unroll
      for (int d = 0; d < 8; ++d) p += q[d] * kv[j][d];
      sc[j] = p;
    }
    // reduce over the 8 lanes of this window (masks 1,2,4 stay in-group)
#pragma unroll
    for (int mask = 1; mask <= 4; mask <<= 1)
#pragma unroll
      for (int j = 0; j < 5; ++j) sc[j] += __shfl_xor(sc[j], mask);
#pragma unroll
    for (int j = 0; j < 5; ++j) sc[j] *= 0.125f;  // 1/sqrt(64)
    float mx = sc[0];
#pragma unroll
    for (int j = 1; j < 5; ++j) mx = fmaxf(mx, sc[j]);
    float e[5], sum = 0.f;
#pragma unroll
    for (int j = 0; j < 5; ++j) { e[j] = __expf(sc[j] - mx); sum += e[j]; }
    float inv = 1.0f / sum;
    float o[8];
#pragma unroll
    for (int d = 0; d < 8; ++d) {
      float a = 0.f;
#pragma unroll
      for (int j = 0; j < 5; ++j) a += e[j] * vv[j][d];
      float v2 = a * inv;
      float e2 = __expf(2.0f * v2);
      o[d] = 1.0f - 2.0f / (e2 + 1.0f);  // tanh
    }
    if (sv) {
      size_t oo = ((size_t)b * S + s) * 256 + h * 64 + t * 8;
      *reinterpret_cast<uint4*>(AO + oo) = pack8(o);
    }
  }
}

// ---------------------------------------------------------------------------
// Kernel 4: O-projection + bias + residual + LayerNorm, fused.
// out(64x256 per block) = LN( AO @ Wo^T + bo + x ).  4 waves, each owns a
// 64-row x 64-col quadrant; row stats via 16-lane shuffles + cross-wave LDS.
// ---------------------------------------------------------------------------
__global__ __launch_bounds__(256) void o_gemm_ln(
    const u16* __restrict__ AO, const u16* __restrict__ Wob,
    const float* __restrict__ bo, const float* __restrict__ x,
    const float* __restrict__ gamma, const float* __restrict__ beta,
    float* __restrict__ out) {
  __shared__ u16 As[64][40];
  __shared__ u16 Bs[256][40];
  __shared__ float pS[4][64], pQ[4][64];
  __shared__ float muS[64], rsS[64];
  const int bm = blockIdx.x;  // 0..1023
  const int tid = threadIdx.x;
  const int lane = tid & 63;
  const int wid = tid >> 6;
  const int wn = wid * 64;
  const int fr = lane & 15;
  const int fq = lane >> 4;

  f32x4 acc[4][4] = {};

  const int ar = tid >> 2;          // A staging: 64 rows x 4 thr/row
  const int ac = (tid & 3) << 3;    // 8-elem chunks
  const u16* Ag = AO + (size_t)(bm * 64 + ar) * 256 + ac;

  for (int kt = 0; kt < 8; ++kt) {
    uint4 a = *reinterpret_cast<const uint4*>(Ag + kt * 32);
    uint4 bvv[4];
#pragma unroll
    for (int j = 0; j < 4; ++j)
      bvv[j] = *reinterpret_cast<const uint4*>(Wob + (size_t)(ar + j * 64) * 256 + kt * 32 + ac);
    __syncthreads();
    *reinterpret_cast<uint4*>(&As[ar][ac]) = a;
#pragma unroll
    for (int j = 0; j < 4; ++j)
      *reinterpret_cast<uint4*>(&Bs[ar + j * 64][ac]) = bvv[j];
    __syncthreads();
    bf16x8 af[4], bf[4];
#pragma unroll
    for (int m = 0; m < 4; ++m)
      af[m] = *reinterpret_cast<const bf16x8*>(&As[m * 16 + fr][fq * 8]);
#pragma unroll
    for (int n = 0; n < 4; ++n)
      bf[n] = *reinterpret_cast<const bf16x8*>(&Bs[wn + n * 16 + fr][fq * 8]);
#pragma unroll
    for (int m = 0; m < 4; ++m)
#pragma unroll
      for (int n = 0; n < 4; ++n)
        acc[m][n] = __builtin_amdgcn_mfma_f32_16x16x32_bf16(af[m], bf[n], acc[m][n], 0, 0, 0);
  }

  // epilogue: acc += bo + x  (residual), then LN stats
  float bov[4], gv[4], bev[4];
#pragma unroll
  for (int n = 0; n < 4; ++n) {
    int c = wn + n * 16 + fr;
    bov[n] = bo[c]; gv[n] = gamma[c]; bev[n] = beta[c];
  }
#pragma unroll
  for (int m = 0; m < 4; ++m)
#pragma unroll
    for (int r = 0; r < 4; ++r) {
      size_t rg = (size_t)(bm * 64 + m * 16 + fq * 4 + r);
#pragma unroll
      for (int n = 0; n < 4; ++n)
        acc[m][n][r] += bov[n] + x[rg * 256 + wn + n * 16 + fr];
    }

#pragma unroll
  for (int m = 0; m < 4; ++m)
#pragma unroll
    for (int r = 0; r < 4; ++r) {
      float s1 = 0.f, s2 = 0.f;
#pragma unroll
      for (int n = 0; n < 4; ++n) {
        float vx = acc[m][n][r];
        s1 += vx; s2 += vx * vx;
      }
#pragma unroll
      for (int mask = 1; mask <= 8; mask <<= 1) {
        s1 += __shfl_xor(s1, mask);
        s2 += __shfl_xor(s2, mask);
      }
      if (fr == 0) {
        int row = m * 16 + fq * 4 + r;
        pS[wid][row] = s1; pQ[wid][row] = s2;
      }
    }
  __syncthreads();
  if (tid < 64) {
    float s1 = pS[0][tid] + pS[1][tid] + pS[2][tid] + pS[3][tid];
    float s2 = pQ[0][tid] + pQ[1][tid] + pQ[2][tid] + pQ[3][tid];
    float mu = s1 * (1.0f / 256.0f);
    float var = s2 * (1.0f / 256.0f) - mu * mu;
    muS[tid] = mu;
    rsS[tid] = rsqrtf(var + 1e-5f);
  }
  __syncthreads();
#pragma unroll
  for (int m = 0; m < 4; ++m)
#pragma unroll
    for (int r = 0; r < 4; ++r) {
      int row = m * 16 + fq * 4 + r;
      float mu = muS[row], rs = rsS[row];
      float* orow = out + (size_t)(bm * 64 + row) * 256;
#pragma unroll
      for (int n = 0; n < 4; ++n)
        orow[wn + n * 16 + fr] = (acc[m][n][r] - mu) * rs * gv[n] + bev[n];
    }
}

// ---------------------------------------------------------------------------
extern "C" void kernel_launch(void* const* d_in, const int* in_sizes, int n_in,
                              void* d_out, int out_size, void* d_ws, size_t ws_size,
                              hipStream_t stream) {
  const float* x     = (const float*)d_in[0];
  const float* Wq    = (const float*)d_in[1];
  const float* bq    = (const float*)d_in[2];
  const float* Wk    = (const float*)d_in[3];
  const float* bk    = (const float*)d_in[4];
  const float* Wv    = (const float*)d_in[5];
  const float* bv    = (const float*)d_in[6];
  const float* Wo    = (const float*)d_in[7];
  const float* bo    = (const float*)d_in[8];
  const float* gamma = (const float*)d_in[9];
  const float* beta  = (const float*)d_in[10];
  float* out = (float*)d_out;

  char* ws = (char*)d_ws;
  u16* xb   = (u16*)(ws);                    // 65536x256 bf16   = 33,554,432 B
  u16* wqkv = (u16*)(ws + 33554432);         // 768x256 bf16     =    393,216 B
  u16* wob  = (u16*)(ws + 33947648);         // 256x256 bf16     =    131,072 B
  u16* qkv  = (u16*)(ws + 34078720);         // 65536x768 bf16   = 100,663,296 B
  u16* ao   = (u16*)(ws + 134742016);        // 65536x256 bf16   = 33,554,432 B
                                             // total ≈ 160.5 MiB

  convert_kernel<<<16640, 256, 0, stream>>>(x, Wq, Wk, Wv, Wo, xb, wqkv, wob);
  dim3 g1(6, 512);
  qkv_gemm<<<g1, 256, 0, stream>>>(xb, wqkv, bq, bk, bv, qkv);
  attn_kernel<<<1640, 256, 0, stream>>>(qkv, ao);
  o_gemm_ln<<<1024, 256, 0, stream>>>(ao, wob, bo, x, gamma, beta, out);
}